// Round 3
// baseline (779.815 us; speedup 1.0000x reference)
//
#include <hip/hip_runtime.h>
#include <hip/hip_bf16.h>
#include <stdint.h>

#define D    256   // hidden dim
#define K2   512   // 2*D (GEMM K, q_star width)
#define G4   1024  // 4*D (gate count)
#define MAXN_LDS 2048

typedef __attribute__((ext_vector_type(8))) short  short8;
typedef __attribute__((ext_vector_type(4))) float  float4v;

__device__ inline short f2bf(float v) {
    __hip_bfloat16 b = __float2bfloat16(v);
    union { __hip_bfloat16 b; unsigned short u; } cv; cv.b = b;
    return (short)cv.u;
}
__device__ inline float bfs2f(short s) {
    union { unsigned int i; float f; } v;
    v.i = ((unsigned int)(unsigned short)s) << 16;
    return v.f;
}

// ---- per-graph boundaries: start[g] = first node with seg >= g --------------
__global__ void k_bounds(const int* __restrict__ seg, int N, int B,
                         int* __restrict__ start) {
    int g = blockIdx.x * blockDim.x + threadIdx.x;
    if (g > B) return;
    int lo = 0, hi = N;
    while (lo < hi) { int mid = (lo + hi) >> 1; if (seg[mid] < g) lo = mid + 1; else hi = mid; }
    start[g] = lo;
}

// ---- Wc = [W_ih[:, :D] + W_hh | W_ih[:, D:2D]] split into bf16 hi+lo --------
__global__ void k_prep(const float* __restrict__ Wih,
                       const float* __restrict__ Whh,
                       const float* __restrict__ bih,
                       const float* __restrict__ bhh,
                       short* __restrict__ Wch, short* __restrict__ Wcl,
                       float* __restrict__ bsum) {
    int idx = blockIdx.x * blockDim.x + threadIdx.x;
    if (idx >= G4 * K2) return;
    int r = idx >> 9, cc = idx & (K2 - 1);
    float v = Wih[idx];
    if (cc < D) v += Whh[r * D + cc];
    short hi = f2bf(v);
    Wch[idx] = hi;
    Wcl[idx] = f2bf(v - bfs2f(hi));
    if (idx < G4) bsum[idx] = bih[idx] + bhh[idx];
}

// ---- fused gates GEMM + LSTM pointwise --------------------------------------
// grid (B/16, 4), 256 thr. Wave w of block (bm,cg) owns m-rows [bm*16,+16) and
// hidden dims j in [cg*64 + w*16, +16), computing all 4 gate groups (rows
// j + g*256 of Wc) so the pointwise stays in registers. A (=X, fp32) is
// converted to bf16 hi/lo on the fly; A.B ~ Ah.Bh + Al.Bh + Ah.Bl.
__global__ __launch_bounds__(256) void k_gemm_lstm(
        const float* __restrict__ X,
        const short* __restrict__ Wch, const short* __restrict__ Wcl,
        const float* __restrict__ bsum,
        float* __restrict__ c, float* __restrict__ h) {
    int wave = threadIdx.x >> 6, lane = threadIdx.x & 63;
    int row = lane & 15, quad = lane >> 4;
    int m0 = blockIdx.x * 16;
    int jbase = blockIdx.y * 64 + wave * 16;
    const float* pa  = X   + (size_t)(m0 + row) * K2 + quad * 8;
    const short* pbh = Wch + (size_t)(jbase + row) * K2 + quad * 8;
    const short* pbl = Wcl + (size_t)(jbase + row) * K2 + quad * 8;
    float4v acc0 = {0,0,0,0}, acc1 = {0,0,0,0}, acc2 = {0,0,0,0}, acc3 = {0,0,0,0};
#pragma unroll
    for (int k = 0; k < K2; k += 32) {
        float4v af0 = *(const float4v*)(pa + k);
        float4v af1 = *(const float4v*)(pa + k + 4);
        short8 ahi, alo;
#pragma unroll
        for (int q = 0; q < 4; q++) {
            float v = af0[q];
            short hi = f2bf(v);
            ahi[q] = hi; alo[q] = f2bf(v - bfs2f(hi));
        }
#pragma unroll
        for (int q = 0; q < 4; q++) {
            float v = af1[q];
            short hi = f2bf(v);
            ahi[q + 4] = hi; alo[q + 4] = f2bf(v - bfs2f(hi));
        }
#define GATE_MFMA(ACC, OFF)                                                        \
        {                                                                          \
            short8 bh = *(const short8*)(pbh + (size_t)(OFF) * K2 + k);            \
            short8 bl = *(const short8*)(pbl + (size_t)(OFF) * K2 + k);            \
            ACC = __builtin_amdgcn_mfma_f32_16x16x32_bf16(ahi, bh, ACC, 0, 0, 0);  \
            ACC = __builtin_amdgcn_mfma_f32_16x16x32_bf16(alo, bh, ACC, 0, 0, 0);  \
            ACC = __builtin_amdgcn_mfma_f32_16x16x32_bf16(ahi, bl, ACC, 0, 0, 0);  \
        }
        GATE_MFMA(acc0, 0)
        GATE_MFMA(acc1, 256)
        GATE_MFMA(acc2, 512)
        GATE_MFMA(acc3, 768)
#undef GATE_MFMA
    }
    // C/D layout: col = lane&15 (N dim = j), row = quad*4 + i (M dim = batch)
    int j = jbase + (lane & 15);
    float bi = bsum[j], bf_ = bsum[j + 256], bg = bsum[j + 512], bo = bsum[j + 768];
#pragma unroll
    for (int i = 0; i < 4; i++) {
        int m = m0 + quad * 4 + i;
        size_t ix = (size_t)m * D + j;
        float gi = acc0[i] + bi, gf = acc1[i] + bf_, gg = acc2[i] + bg, go = acc3[i] + bo;
        float si = 1.f / (1.f + __expf(-gi));
        float sf = 1.f / (1.f + __expf(-gf));
        float so = 1.f / (1.f + __expf(-go));
        float cn = sf * c[ix] + si * tanhf(gg);
        float hn = so * tanhf(cn);
        c[ix] = cn;
        h[ix] = hn;
    }
}

// ---- attention: publish h->X[:, :D], e=feat.q, softmax, readout->X[:, D:2D] -
__global__ __launch_bounds__(256) void k_attn(const float* __restrict__ feat,
                                              const int* __restrict__ start,
                                              const float* __restrict__ h,
                                              float* __restrict__ X, int N) {
    __shared__ __align__(16) float q_l[D];
    __shared__ float e_l[MAXN_LDS];
    __shared__ float redm[4], reds[4];
    int g = blockIdx.x;
    int t = threadIdx.x;
    int lane = t & 63, wave = t >> 6;
    // publish h into X row g (block g owns row g -> race-free)
    float hv = h[(size_t)g * D + t];
    q_l[t] = hv;
    X[(size_t)g * K2 + t] = hv;
    int s = start[g], e = start[g + 1];
    s = max(0, min(s, N)); e = max(s, min(e, N));   // defensive clamp
    int cnt = e - s;
    __syncthreads();
    if (cnt <= 0) {
        X[(size_t)g * K2 + D + t] = 0.f;
        return;
    }
    if (cnt > MAXN_LDS) cnt = MAXN_LDS;  // never hit at N/B~195

    // phase 1: e[n] = <feat[n], q>, one wave per node, float4/lane = 1KB row
    float4v qv = *(const float4v*)(q_l + lane * 4);
    for (int n = wave; n < cnt; n += 4) {
        float4v u = *((const float4v*)(feat + (size_t)(s + n) * D) + lane);
        float sum = u.x * qv.x + u.y * qv.y + u.z * qv.z + u.w * qv.w;
#pragma unroll
        for (int m = 1; m < 64; m <<= 1) sum += __shfl_xor(sum, m, 64);
        if (lane == 0) e_l[n] = sum;
    }
    __syncthreads();

    // phase 2: stable softmax over e_l[0..cnt)
    float lmax = -3.4e38f;
    for (int i = t; i < cnt; i += 256) lmax = fmaxf(lmax, e_l[i]);
#pragma unroll
    for (int m = 1; m < 64; m <<= 1) lmax = fmaxf(lmax, __shfl_xor(lmax, m, 64));
    if (lane == 0) redm[wave] = lmax;
    __syncthreads();
    float emax = fmaxf(fmaxf(redm[0], redm[1]), fmaxf(redm[2], redm[3]));
    float lsum = 0.f;
    for (int i = t; i < cnt; i += 256) {
        float v = __expf(e_l[i] - emax);
        e_l[i] = v;
        lsum += v;
    }
#pragma unroll
    for (int m = 1; m < 64; m <<= 1) lsum += __shfl_xor(lsum, m, 64);
    if (lane == 0) reds[wave] = lsum;
    __syncthreads();
    float inv = 1.f / (reds[0] + reds[1] + reds[2] + reds[3]);
    for (int i = t; i < cnt; i += 256) e_l[i] *= inv;
    __syncthreads();

    // phase 3: readout[d] = sum_n alpha[n]*feat[n][d]; thread t owns dim t
    const float* colp = feat + (size_t)s * D + t;
    float acc = 0.f;
#pragma unroll 4
    for (int i = 0; i < cnt; i++) acc += e_l[i] * colp[(size_t)i * D];
    X[(size_t)g * K2 + D + t] = acc;
}

extern "C" void kernel_launch(void* const* d_in, const int* in_sizes, int n_in,
                              void* d_out, int out_size, void* d_ws, size_t ws_size,
                              hipStream_t stream) {
    const float* feat = (const float*)d_in[0];
    const float* Wih  = (const float*)d_in[1];
    const float* Whh  = (const float*)d_in[2];
    const float* bih  = (const float*)d_in[3];
    const float* bhh  = (const float*)d_in[4];
    const int*   seg  = (const int*)d_in[5];
    const int N = in_sizes[5];
    const int B = out_size / K2;   // 1024

    // ws layout (~4.01 MB): c | h | Wch | Wcl | bsum | start
    char* ws = (char*)d_ws;
    size_t szC = (size_t)B * D * sizeof(float);            // 1 MB
    float* c   = (float*)ws;
    float* h   = (float*)(ws + szC);
    short* Wch = (short*)(ws + 2 * szC);                   // 1 MB
    short* Wcl = (short*)(ws + 2 * szC + (size_t)G4 * K2 * sizeof(short));
    float* bsum = (float*)(ws + 2 * szC + 2 * (size_t)G4 * K2 * sizeof(short));
    int*   start = (int*)((char*)bsum + (size_t)G4 * sizeof(float));

    float* X = (float*)d_out;                              // q_star [B, 2D] fp32

    hipMemsetAsync(ws, 0, 2 * szC, stream);                              // c, h = 0
    hipMemsetAsync(d_out, 0, (size_t)B * K2 * sizeof(float), stream);    // X = 0
    k_prep<<<(G4 * K2 + 255) / 256, 256, 0, stream>>>(Wih, Whh, bih, bhh, Wch, Wcl, bsum);
    k_bounds<<<(B + 1 + 255) / 256, 256, 0, stream>>>(seg, N, B, start);

    for (int it = 0; it < 6; it++) {
        k_gemm_lstm<<<dim3(B / 16, 4), 256, 0, stream>>>(X, Wch, Wcl, bsum, c, h);
        k_attn<<<B, 256, 0, stream>>>(feat, start, h, X, N);
    }
}

// Round 4
// 602.734 us; speedup vs baseline: 1.2938x; 1.2938x over previous
//
#include <hip/hip_runtime.h>
#include <hip/hip_bf16.h>
#include <stdint.h>

#define D    256   // hidden dim
#define K2   512   // 2*D (GEMM K, q_star width)
#define G4   1024  // 4*D (gate count)

typedef __attribute__((ext_vector_type(8))) short  short8;
typedef __attribute__((ext_vector_type(4))) float  float4v;

__device__ inline short f2bf(float v) {
    __hip_bfloat16 b = __float2bfloat16(v);
    union { __hip_bfloat16 b; unsigned short u; } cv; cv.b = b;
    return (short)cv.u;
}
__device__ inline float bfs2f(short s) {
    union { unsigned int i; float f; } v;
    v.i = ((unsigned int)(unsigned short)s) << 16;
    return v.f;
}

// ---- per-graph boundaries: start[g] = first node with seg >= g --------------
__global__ void k_bounds(const int* __restrict__ seg, int N, int B,
                         int* __restrict__ start) {
    int g = blockIdx.x * blockDim.x + threadIdx.x;
    if (g > B) return;
    int lo = 0, hi = N;
    while (lo < hi) { int mid = (lo + hi) >> 1; if (seg[mid] < g) lo = mid + 1; else hi = mid; }
    start[g] = lo;
}

// ---- Wc = [W_ih[:, :D] + W_hh | W_ih[:, D:2D]] split into bf16 hi+lo --------
__global__ void k_prep(const float* __restrict__ Wih,
                       const float* __restrict__ Whh,
                       const float* __restrict__ bih,
                       const float* __restrict__ bhh,
                       short* __restrict__ Wch, short* __restrict__ Wcl,
                       float* __restrict__ bsum) {
    int idx = blockIdx.x * blockDim.x + threadIdx.x;
    if (idx >= G4 * K2) return;
    int r = idx >> 9, cc = idx & (K2 - 1);
    float v = Wih[idx];
    if (cc < D) v += Whh[r * D + cc];
    short hi = f2bf(v);
    Wch[idx] = hi;
    Wcl[idx] = f2bf(v - bfs2f(hi));
    if (idx < G4) bsum[idx] = bih[idx] + bhh[idx];
}

// ---- fused gates GEMM + LSTM pointwise --------------------------------------
// grid (B/16, 4), 256 thr. Wave w of block (bm,cg) owns m-rows [bm*16,+16) and
// hidden dims j in [cg*64 + w*16, +16), computing all 4 gate groups (rows
// j + g*256 of Wc) so the pointwise stays in registers. A (=X, fp32) is
// converted to bf16 hi/lo on the fly; A.B ~ Ah.Bh + Al.Bh + Ah.Bl (~fp22).
__global__ __launch_bounds__(256) void k_gemm_lstm(
        const float* __restrict__ X,
        const short* __restrict__ Wch, const short* __restrict__ Wcl,
        const float* __restrict__ bsum,
        float* __restrict__ c, float* __restrict__ h) {
    int wave = threadIdx.x >> 6, lane = threadIdx.x & 63;
    int row = lane & 15, quad = lane >> 4;
    int m0 = blockIdx.x * 16;
    int jbase = blockIdx.y * 64 + wave * 16;
    const float* pa  = X   + (size_t)(m0 + row) * K2 + quad * 8;
    const short* pbh = Wch + (size_t)(jbase + row) * K2 + quad * 8;
    const short* pbl = Wcl + (size_t)(jbase + row) * K2 + quad * 8;
    float4v acc0 = {0,0,0,0}, acc1 = {0,0,0,0}, acc2 = {0,0,0,0}, acc3 = {0,0,0,0};
#pragma unroll
    for (int k = 0; k < K2; k += 32) {
        float4v af0 = *(const float4v*)(pa + k);
        float4v af1 = *(const float4v*)(pa + k + 4);
        short8 ahi, alo;
#pragma unroll
        for (int q = 0; q < 4; q++) {
            float v = af0[q];
            short hi = f2bf(v);
            ahi[q] = hi; alo[q] = f2bf(v - bfs2f(hi));
        }
#pragma unroll
        for (int q = 0; q < 4; q++) {
            float v = af1[q];
            short hi = f2bf(v);
            ahi[q + 4] = hi; alo[q + 4] = f2bf(v - bfs2f(hi));
        }
#define GATE_MFMA(ACC, OFF)                                                        \
        {                                                                          \
            short8 bh = *(const short8*)(pbh + (size_t)(OFF) * K2 + k);            \
            short8 bl = *(const short8*)(pbl + (size_t)(OFF) * K2 + k);            \
            ACC = __builtin_amdgcn_mfma_f32_16x16x32_bf16(ahi, bh, ACC, 0, 0, 0);  \
            ACC = __builtin_amdgcn_mfma_f32_16x16x32_bf16(alo, bh, ACC, 0, 0, 0);  \
            ACC = __builtin_amdgcn_mfma_f32_16x16x32_bf16(ahi, bl, ACC, 0, 0, 0);  \
        }
        GATE_MFMA(acc0, 0)
        GATE_MFMA(acc1, 256)
        GATE_MFMA(acc2, 512)
        GATE_MFMA(acc3, 768)
#undef GATE_MFMA
    }
    // C/D layout: col = lane&15 (N dim = j), row = quad*4 + i (M dim = batch)
    int j = jbase + (lane & 15);
    float bi = bsum[j], bf_ = bsum[j + 256], bg = bsum[j + 512], bo = bsum[j + 768];
#pragma unroll
    for (int i = 0; i < 4; i++) {
        int m = m0 + quad * 4 + i;
        size_t ix = (size_t)m * D + j;
        float gi = acc0[i] + bi, gf = acc1[i] + bf_, gg = acc2[i] + bg, go = acc3[i] + bo;
        float si = 1.f / (1.f + __expf(-gi));
        float sf = 1.f / (1.f + __expf(-gf));
        float so = 1.f / (1.f + __expf(-go));
        float cn = sf * c[ix] + si * tanhf(gg);
        float hn = so * tanhf(cn);
        c[ix] = cn;
        h[ix] = hn;
    }
}

// ---- attention, single pass over feat (flash-style online softmax) ----------
// Block g handles graph g. Each wave keeps running (m, l, acc[256]) with lane
// owning dims lane*4..lane*4+3 (exactly its float4 row slice). 4 rows per step
// for ILP on the shuffle reductions. Waves merge via 4 KB LDS at the end.
__global__ __launch_bounds__(256) void k_attn(const float* __restrict__ feat,
                                              const int* __restrict__ start,
                                              const float* __restrict__ h,
                                              float* __restrict__ X, int N) {
    __shared__ float accs[4 * D];
    __shared__ float ms[4], ls[4];
    int g = blockIdx.x;
    int t = threadIdx.x;
    int lane = t & 63, wave = t >> 6;
    // publish h into X row g (block g owns row g -> race-free)
    float hv = h[(size_t)g * D + t];
    X[(size_t)g * K2 + t] = hv;
    int s = start[g], e = start[g + 1];
    s = max(0, min(s, N)); e = max(s, min(e, N));   // defensive clamp
    int cnt = e - s;
    if (cnt <= 0) {                                  // block-uniform
        X[(size_t)g * K2 + D + t] = 0.f;
        return;
    }
    const float NEG = -3.0e38f;
    float4v q = *(const float4v*)(h + (size_t)g * D + lane * 4);
    float m = NEG, l = 0.f;
    float4v acc = {0.f, 0.f, 0.f, 0.f};

    for (int n0 = wave * 4; n0 < cnt; n0 += 16) {
        float4v rows[4];
        float ev[4];
#pragma unroll
        for (int r = 0; r < 4; r++) {
            int ci = (n0 + r < cnt) ? (s + n0 + r) : (s + n0);  // clamp: no OOB read
            rows[r] = *((const float4v*)(feat + (size_t)ci * D) + lane);
            ev[r] = rows[r].x * q.x + rows[r].y * q.y + rows[r].z * q.z + rows[r].w * q.w;
        }
#pragma unroll
        for (int step = 1; step < 64; step <<= 1) {
#pragma unroll
            for (int r = 0; r < 4; r++) ev[r] += __shfl_xor(ev[r], step, 64);
        }
        float mnew = m;
#pragma unroll
        for (int r = 0; r < 4; r++) {
            if (n0 + r >= cnt) ev[r] = NEG;
            mnew = fmaxf(mnew, ev[r]);
        }
        float alpha = __expf(m - mnew);               // NEG-NEG -> exp(0)=1, l=0 anyway
        float w[4];
#pragma unroll
        for (int r = 0; r < 4; r++)
            w[r] = (n0 + r < cnt) ? __expf(ev[r] - mnew) : 0.f;
        l = l * alpha + w[0] + w[1] + w[2] + w[3];
        acc.x *= alpha; acc.y *= alpha; acc.z *= alpha; acc.w *= alpha;
#pragma unroll
        for (int r = 0; r < 4; r++) {
            acc.x += w[r] * rows[r].x;
            acc.y += w[r] * rows[r].y;
            acc.z += w[r] * rows[r].z;
            acc.w += w[r] * rows[r].w;
        }
        m = mnew;
    }

    // merge 4 waves
    *((float4v*)(accs + wave * D + lane * 4)) = acc;
    if (lane == 0) { ms[wave] = m; ls[wave] = l; }
    __syncthreads();
    float mt = fmaxf(fmaxf(ms[0], ms[1]), fmaxf(ms[2], ms[3]));
    float s0 = __expf(ms[0] - mt), s1 = __expf(ms[1] - mt);
    float s2 = __expf(ms[2] - mt), s3 = __expf(ms[3] - mt);
    float lt = ls[0] * s0 + ls[1] * s1 + ls[2] * s2 + ls[3] * s3;
    float val = accs[t] * s0 + accs[D + t] * s1 + accs[2 * D + t] * s2 + accs[3 * D + t] * s3;
    X[(size_t)g * K2 + D + t] = val / lt;
}

extern "C" void kernel_launch(void* const* d_in, const int* in_sizes, int n_in,
                              void* d_out, int out_size, void* d_ws, size_t ws_size,
                              hipStream_t stream) {
    const float* feat = (const float*)d_in[0];
    const float* Wih  = (const float*)d_in[1];
    const float* Whh  = (const float*)d_in[2];
    const float* bih  = (const float*)d_in[3];
    const float* bhh  = (const float*)d_in[4];
    const int*   seg  = (const int*)d_in[5];
    const int N = in_sizes[5];
    const int B = out_size / K2;   // 1024

    // ws layout (~4.01 MB): c | h | Wch | Wcl | bsum | start
    char* ws = (char*)d_ws;
    size_t szC = (size_t)B * D * sizeof(float);            // 1 MB
    float* c   = (float*)ws;
    float* h   = (float*)(ws + szC);
    short* Wch = (short*)(ws + 2 * szC);                   // 1 MB
    short* Wcl = (short*)(ws + 2 * szC + (size_t)G4 * K2 * sizeof(short));
    float* bsum = (float*)(ws + 2 * szC + 2 * (size_t)G4 * K2 * sizeof(short));
    int*   start = (int*)((char*)bsum + (size_t)G4 * sizeof(float));

    float* X = (float*)d_out;                              // q_star [B, 2D] fp32

    hipMemsetAsync(ws, 0, 2 * szC, stream);                              // c, h = 0
    hipMemsetAsync(d_out, 0, (size_t)B * K2 * sizeof(float), stream);    // X = 0
    k_prep<<<(G4 * K2 + 255) / 256, 256, 0, stream>>>(Wih, Whh, bih, bhh, Wch, Wcl, bsum);
    k_bounds<<<(B + 1 + 255) / 256, 256, 0, stream>>>(seg, N, B, start);

    for (int it = 0; it < 6; it++) {
        k_gemm_lstm<<<dim3(B / 16, 4), 256, 0, stream>>>(X, Wch, Wcl, bsum, c, h);
        k_attn<<<B, 256, 0, stream>>>(feat, start, h, X, N);
    }
}